// Round 1
// baseline (283.397 us; speedup 1.0000x reference)
//
#include <hip/hip_runtime.h>

// QLoRA NF4 forward: out[b,s,o] = 4.0 * sum_r (sum_i x[b,s,i]*W_A[r,i]) * W_B[o,r]
// B=4 S=2048 IN=4096 OUT=4096 R=8, BLOCK(quant)=64. All fp32.
// Memory-bound: floor = 134MB x-read + 134MB out-write ≈ 43us @ 6.3TB/s.

static __device__ __constant__ float NF4_TBL[16] = {
    -1.0f, -0.6961928009986877f, -0.5250730514526367f, -0.39491748809814453f,
    -0.28444138169288635f, -0.18477343022823334f, -0.09105003625154495f, 0.0f,
    0.07958029955625534f, 0.16093020141124725f, 0.24611230194568634f,
    0.33791524171829224f, 0.44070982933044434f, 0.5626170039176941f,
    0.7229568362236328f, 1.0f};

// Dequant both factors into workspace. nA == nB == 32768 here.
__global__ void nf4_dequant_kernel(const int* __restrict__ codesA,
                                   const float* __restrict__ absA,
                                   const int* __restrict__ codesB,
                                   const float* __restrict__ absB,
                                   float* __restrict__ wA,
                                   float* __restrict__ wB,
                                   int n) {
    int id = blockIdx.x * blockDim.x + threadIdx.x;
    if (id < n) {
        wA[id] = NF4_TBL[codesA[id] & 15] * absA[id >> 6];   // flat idx/64 block
        wB[id] = NF4_TBL[codesB[id] & 15] * absB[id >> 6];   // layout [o][r] as-is
    }
}

// One block = 8 rows of x. Phase 1: interm[8][8] = Xrows @ W_A^T (wave w owns
// rows 2w,2w+1; shuffle-reduce). Phase 2: out rows = interm @ W_B^T, W_B rows
// register-cached across the 8-row loop.
__global__ __launch_bounds__(256, 4) void qlora_fused_kernel(
    const float* __restrict__ x,     // [8192, 4096]
    const float* __restrict__ wA,    // [8, 4096]
    const float* __restrict__ wB,    // [4096, 8]
    float* __restrict__ out) {       // [8192, 4096]
    constexpr int IN = 4096;
    constexpr int OUT = 4096;
    constexpr int ROWS = 8;

    __shared__ float interm[ROWS][8];

    const int t    = threadIdx.x;
    const int wave = t >> 6;
    const int lane = t & 63;
    const int row0 = blockIdx.x * ROWS;        // first global row of this block

    // ---- Phase 1: each wave computes interm for rows 2*wave, 2*wave+1 ----
    {
        const int r0 = row0 + 2 * wave;
        const float4* __restrict__ x0  = (const float4*)(x + (size_t)r0 * IN);
        const float4* __restrict__ x1  = (const float4*)(x + (size_t)(r0 + 1) * IN);
        const float4* __restrict__ wA4 = (const float4*)wA;   // [8][1024]

        float acc0[8], acc1[8];
        #pragma unroll
        for (int r = 0; r < 8; ++r) { acc0[r] = 0.f; acc1[r] = 0.f; }

        #pragma unroll 4
        for (int c = 0; c < IN / 4 / 64; ++c) {               // 16 chunks
            const int idx = lane + 64 * c;                    // coalesced per wave
            const float4 xa = x0[idx];
            const float4 xb = x1[idx];
            #pragma unroll
            for (int r = 0; r < 8; ++r) {
                const float4 w = wA4[r * (IN / 4) + idx];
                acc0[r] += xa.x * w.x + xa.y * w.y + xa.z * w.z + xa.w * w.w;
                acc1[r] += xb.x * w.x + xb.y * w.y + xb.z * w.z + xb.w * w.w;
            }
        }

        // width-64 wave reduction of 16 scalars
        #pragma unroll
        for (int r = 0; r < 8; ++r) {
            float v0 = acc0[r], v1 = acc1[r];
            #pragma unroll
            for (int off = 32; off > 0; off >>= 1) {
                v0 += __shfl_down(v0, off, 64);
                v1 += __shfl_down(v1, off, 64);
            }
            if (lane == 0) {
                interm[2 * wave + 0][r] = v0 * 4.0f;          // SCALING folded in
                interm[2 * wave + 1][r] = v1 * 4.0f;
            }
        }
    }
    __syncthreads();

    // ---- Phase 2: out[row0+m][o] = sum_r interm[m][r] * W_B[o][r] ----
    const float4* __restrict__ wB4 = (const float4*)wB;       // row o = wB4[2o],wB4[2o+1]
    #pragma unroll
    for (int k = 0; k < 4; ++k) {
        const int og = t + 256 * k;                           // float4 group, o0 = 4*og
        float4 wrow[8];
        #pragma unroll
        for (int j = 0; j < 8; ++j) wrow[j] = wB4[8 * og + j];

        #pragma unroll
        for (int m = 0; m < ROWS; ++m) {
            const float4 i0 = ((const float4*)interm[m])[0];
            const float4 i1 = ((const float4*)interm[m])[1];
            float4 s;
            s.x = i0.x * wrow[0].x + i0.y * wrow[0].y + i0.z * wrow[0].z + i0.w * wrow[0].w
                + i1.x * wrow[1].x + i1.y * wrow[1].y + i1.z * wrow[1].z + i1.w * wrow[1].w;
            s.y = i0.x * wrow[2].x + i0.y * wrow[2].y + i0.z * wrow[2].z + i0.w * wrow[2].w
                + i1.x * wrow[3].x + i1.y * wrow[3].y + i1.z * wrow[3].z + i1.w * wrow[3].w;
            s.z = i0.x * wrow[4].x + i0.y * wrow[4].y + i0.z * wrow[4].z + i0.w * wrow[4].w
                + i1.x * wrow[5].x + i1.y * wrow[5].y + i1.z * wrow[5].z + i1.w * wrow[5].w;
            s.w = i0.x * wrow[6].x + i0.y * wrow[6].y + i0.z * wrow[6].z + i0.w * wrow[6].w
                + i1.x * wrow[7].x + i1.y * wrow[7].y + i1.z * wrow[7].z + i1.w * wrow[7].w;
            ((float4*)(out + (size_t)(row0 + m) * OUT))[og] = s;   // coalesced
        }
    }
}

extern "C" void kernel_launch(void* const* d_in, const int* in_sizes, int n_in,
                              void* d_out, int out_size, void* d_ws, size_t ws_size,
                              hipStream_t stream) {
    const float* x       = (const float*)d_in[0];
    const int*   codes_A = (const int*)d_in[1];
    const float* absmax_A= (const float*)d_in[2];
    const int*   codes_B = (const int*)d_in[3];
    const float* absmax_B= (const float*)d_in[4];
    float* out = (float*)d_out;

    constexpr int NW = 8 * 4096;   // elements in each weight factor
    float* wA = (float*)d_ws;                  // 128 KB
    float* wB = (float*)d_ws + NW;             // 128 KB

    nf4_dequant_kernel<<<(NW + 255) / 256, 256, 0, stream>>>(
        codes_A, absmax_A, codes_B, absmax_B, wA, wB, NW);

    const int n_rows = 4 * 2048;               // B*S
    qlora_fused_kernel<<<n_rows / 8, 256, 0, stream>>>(x, wA, wB, out);
}